// Round 4
// baseline (5661.232 us; speedup 1.0000x reference)
//
#include <hip/hip_runtime.h>

// LIF recurrent network — persistent dataflow kernel, zero barriers.
// 128 WGs x 256 threads (cooperative launch for co-residency only).
// Spike exchange: per-step mask buffers maskbuf[t][128] (u64) + step-tagged
// flags[t][128] (u32, value t+1) in ws. Producer: release-store word+flag.
// Consumer: wave 0 acquire-polls all 128 flags of step t (2/lane), decodes
// in fixed order (deterministic FP accumulation), 4 waves gather, wave 0
// updates register-resident state (v, I) and writes traces. Buffers are
// never recycled -> WGs may drift across steps; no grid sync ever.
// Fallback to chained per-step kernels if ws_size is too small.

constexpr int N_NEUR  = 8192;
constexpr int NWORDS  = N_NEUR / 64;   // 128 mask words
constexpr int NWG     = 128;
constexpr int TPB     = 256;           // 4 waves
constexpr int N_STEPS = 500;

// ws layout (persistent path)
constexpr size_t MASK_BYTES = (size_t)(N_STEPS + 1) * NWORDS * 8;  // 513,024
constexpr size_t FLAG_OFF   = MASK_BYTES;
constexpr size_t FLAG_BYTES = (size_t)(N_STEPS + 1) * NWORDS * 4;  // 256,512
constexpr size_t WS_NEEDED  = FLAG_OFF + FLAG_BYTES;

// ---------------- persistent path ----------------

__global__ __launch_bounds__(256) void lif_dfinit(
    unsigned long long* __restrict__ maskbuf,
    unsigned int*       __restrict__ flags)
{
    const int i = blockIdx.x * blockDim.x + threadIdx.x;
    const int nflags = (N_STEPS + 1) * NWORDS;
    for (int k = i; k < nflags; k += gridDim.x * blockDim.x)
        flags[k] = (k < NWORDS) ? 1u : 0u;     // step-0 masks valid
    if (i < NWORDS) maskbuf[i] = 0ull;         // no spikes enter step 0
}

__global__ __launch_bounds__(TPB) void lif_persist(
    const float* __restrict__ inputs,
    const float* __restrict__ Wt,          // [N][N] row-major, row = presyn
    const int*   __restrict__ ntypes,
    const float* __restrict__ pEw,
    const float* __restrict__ pIw,
    const float* __restrict__ pEvth,
    const float* __restrict__ pIvth,
    const int*   __restrict__ pnsteps,
    float*       __restrict__ out,         // (2, n_steps, N) f32
    unsigned long long* __restrict__ maskbuf,
    unsigned int*       __restrict__ flags)
{
    const int tid  = threadIdx.x;
    const int g    = blockIdx.x;
    const int w    = tid >> 6;
    const int lane = tid & 63;
    const int c    = (g << 6) + lane;

    __shared__ float          s_scale[N_NEUR];   // 32 KiB
    __shared__ unsigned short s_idx[N_NEUR];     // 16 KiB
    __shared__ float          s_red[4][64];
    __shared__ int            s_n;

    const float Ew = *pEw, Iw = *pIw;
    for (int i = tid; i < N_NEUR; i += TPB)
        s_scale[i] = (ntypes[i] == 1) ? Ew : -Iw;

    float v_st = 0.f, I_st = 0.f, inp = 0.f, vth = 0.f;
    if (tid < 64) {
        inp = inputs[c];
        vth = (ntypes[c] == 1) ? *pEvth : *pIvth;
    }
    const int n_steps = min(*pnsteps, N_STEPS);
    const float alpha = expf(-0.1f);   // exp(-DT/TAU_M)
    const float beta  = expf(-0.2f);   // exp(-DT/TAU_I)
    __syncthreads();

    for (int t = 0; t < n_steps; ++t) {
        // ---- wave 0: wait + decode step-t masks (fixed order) ----
        if (w == 0) {
            const unsigned tag = (unsigned)(t + 1);
            const int fi0 = t * NWORDS + 2 * lane;
            const int fi1 = fi0 + 1;
            bool d0 = false, d1 = false;
            for (;;) {
                if (!d0) d0 = (__hip_atomic_load(&flags[fi0], __ATOMIC_ACQUIRE,
                                                 __HIP_MEMORY_SCOPE_AGENT) == tag);
                if (!d1) d1 = (__hip_atomic_load(&flags[fi1], __ATOMIC_ACQUIRE,
                                                 __HIP_MEMORY_SCOPE_AGENT) == tag);
                if (__all(d0 && d1)) break;
                __builtin_amdgcn_s_sleep(2);
            }
            unsigned long long w0 = maskbuf[fi0];
            unsigned long long w1 = maskbuf[fi1];

            const int cnt = __popcll(w0) + __popcll(w1);
            int incl = cnt;
            #pragma unroll
            for (int d = 1; d < 64; d <<= 1) {
                const int u = __shfl_up(incl, d);
                if (lane >= d) incl += u;
            }
            if (lane == 63) s_n = incl;
            int p = incl - cnt;                    // exclusive prefix
            const int base0 = (2 * lane) << 6;
            while (w0) {
                const int b = __builtin_ctzll(w0); w0 &= w0 - 1;
                s_idx[p++] = (unsigned short)(base0 + b);
            }
            const int base1 = base0 + 64;
            while (w1) {
                const int b = __builtin_ctzll(w1); w1 &= w1 - 1;
                s_idx[p++] = (unsigned short)(base1 + b);
            }
        }
        __syncthreads();

        // ---- gather: 4 waves, stride 4, 4 ILP chains ----
        const int n = s_n;
        float a0 = 0.f, a1 = 0.f, a2 = 0.f, a3 = 0.f;
        int k = w;
        for (; k + 12 < n; k += 16) {
            const int j0 = s_idx[k],     j1 = s_idx[k + 4];
            const int j2 = s_idx[k + 8], j3 = s_idx[k + 12];
            a0 = fmaf(s_scale[j0], Wt[(size_t)j0 * N_NEUR + c], a0);
            a1 = fmaf(s_scale[j1], Wt[(size_t)j1 * N_NEUR + c], a1);
            a2 = fmaf(s_scale[j2], Wt[(size_t)j2 * N_NEUR + c], a2);
            a3 = fmaf(s_scale[j3], Wt[(size_t)j3 * N_NEUR + c], a3);
        }
        for (; k < n; k += 4) {
            const int j = s_idx[k];
            a0 = fmaf(s_scale[j], Wt[(size_t)j * N_NEUR + c], a0);
        }
        s_red[w][lane] = (a0 + a1) + (a2 + a3);
        __syncthreads();

        // ---- wave 0: update register state, write traces, produce t+1 ----
        if (tid < 64) {
            const float rec = (s_red[0][lane] + s_red[1][lane]) +
                              (s_red[2][lane] + s_red[3][lane]);
            I_st = beta * I_st + rec;
            const float vn = alpha * v_st + (1.0f - alpha) * (I_st + inp);
            const bool  spk = (vn >= vth);
            v_st = spk ? 0.0f : vn;

            out[(size_t)t * N_NEUR + c] = v_st;
            out[(size_t)n_steps * N_NEUR + (size_t)t * N_NEUR + c] = spk ? 1.0f : 0.0f;

            const unsigned long long m = __ballot(spk);
            if (lane == 0) {
                const int ni = (t + 1) * NWORDS + g;
                __hip_atomic_store(&maskbuf[ni], m, __ATOMIC_RELAXED,
                                   __HIP_MEMORY_SCOPE_AGENT);
                __hip_atomic_store(&flags[ni], (unsigned)(t + 2), __ATOMIC_RELEASE,
                                   __HIP_MEMORY_SCOPE_AGENT);
            }
        }
        // barrier-free LDS reuse is safe: waves 1-3 park at next-iter sync1
        // until wave 0 finishes its update + next decode.
    }
}

// ---------------- fallback path (round-3 chained nodes) ----------------

__global__ __launch_bounds__(256) void lif_init(
    const int* __restrict__ ntypes,
    const float* __restrict__ pEw, const float* __restrict__ pIw,
    float* __restrict__ scale, float* __restrict__ v, float* __restrict__ I,
    unsigned long long* __restrict__ mask0, unsigned long long* __restrict__ mask1)
{
    const int i = blockIdx.x * blockDim.x + threadIdx.x;
    if (i < N_NEUR) {
        scale[i] = (ntypes[i] == 1) ? *pEw : -(*pIw);
        v[i] = 0.0f; I[i] = 0.0f;
    }
    if (i < NWORDS) { mask0[i] = 0ull; mask1[i] = 0ull; }
}

__global__ __launch_bounds__(TPB) void lif_step(
    const float* __restrict__ inputs, const float* __restrict__ Wt,
    const int* __restrict__ ntypes,
    const float* __restrict__ pEvth, const float* __restrict__ pIvth,
    const int* __restrict__ pnsteps, float* __restrict__ out,
    const float* __restrict__ scale, float* __restrict__ v, float* __restrict__ I,
    const unsigned long long* __restrict__ mask_in,
    unsigned long long* __restrict__ mask_out, int t)
{
    const int tid = threadIdx.x, g = blockIdx.x, w = tid >> 6, lane = tid & 63;
    const int c = (g << 6) + lane;

    __shared__ float s_scale[N_NEUR];
    __shared__ unsigned short s_idx[N_NEUR];
    __shared__ float s_red[4][64];
    __shared__ int s_ws[2];

    unsigned long long word = 0ull;
    if (tid < NWORDS) word = mask_in[tid];

    const float4* sc4 = (const float4*)scale;
    float4* ss4 = (float4*)s_scale;
    #pragma unroll
    for (int i = 0; i < 8; ++i) ss4[tid + (i << 8)] = sc4[tid + (i << 8)];

    float v_old = 0.f, I_old = 0.f, inp = 0.f, vth = 0.f;
    if (tid < 64) {
        v_old = v[c]; I_old = I[c]; inp = inputs[c];
        vth = (ntypes[c] == 1) ? *pEvth : *pIvth;
    }
    const int n_steps = *pnsteps;

    int cnt = 0;
    if (tid < NWORDS) cnt = __popcll(word);
    int incl = cnt;
    #pragma unroll
    for (int d = 1; d < 64; d <<= 1) {
        const int u = __shfl_up(incl, d);
        if (lane >= d) incl += u;
    }
    if (w < 2 && lane == 63) s_ws[w] = incl;
    __syncthreads();

    const int n = s_ws[0] + s_ws[1];
    if (tid < NWORDS) {
        int p = ((w == 1) ? s_ws[0] : 0) + incl - cnt;
        const int base = tid << 6;
        while (word) {
            const int b = __builtin_ctzll(word); word &= word - 1;
            s_idx[p++] = (unsigned short)(base + b);
        }
    }
    __syncthreads();

    float a0 = 0.f, a1 = 0.f, a2 = 0.f, a3 = 0.f;
    int k = w;
    for (; k + 12 < n; k += 16) {
        const int j0 = s_idx[k], j1 = s_idx[k + 4];
        const int j2 = s_idx[k + 8], j3 = s_idx[k + 12];
        a0 = fmaf(s_scale[j0], Wt[(size_t)j0 * N_NEUR + c], a0);
        a1 = fmaf(s_scale[j1], Wt[(size_t)j1 * N_NEUR + c], a1);
        a2 = fmaf(s_scale[j2], Wt[(size_t)j2 * N_NEUR + c], a2);
        a3 = fmaf(s_scale[j3], Wt[(size_t)j3 * N_NEUR + c], a3);
    }
    for (; k < n; k += 4) {
        const int j = s_idx[k];
        a0 = fmaf(s_scale[j], Wt[(size_t)j * N_NEUR + c], a0);
    }
    s_red[w][lane] = (a0 + a1) + (a2 + a3);
    __syncthreads();

    if (tid < 64) {
        const float rec = (s_red[0][lane] + s_red[1][lane]) +
                          (s_red[2][lane] + s_red[3][lane]);
        const float alpha = expf(-0.1f), beta = expf(-0.2f);
        const float I_new = beta * I_old + rec;
        const float vn = alpha * v_old + (1.0f - alpha) * (I_new + inp);
        const bool spk = (vn >= vth);
        const float vr = spk ? 0.0f : vn;
        if (t < n_steps) {
            out[(size_t)t * N_NEUR + c] = vr;
            out[(size_t)n_steps * N_NEUR + (size_t)t * N_NEUR + c] = spk ? 1.0f : 0.0f;
            v[c] = vr; I[c] = I_new;
            const unsigned long long m = __ballot(spk);
            if (lane == 0) mask_out[g] = m;
        }
    }
}

extern "C" void kernel_launch(void* const* d_in, const int* in_sizes, int n_in,
                              void* d_out, int out_size, void* d_ws, size_t ws_size,
                              hipStream_t stream) {
    const float* inputs = (const float*)d_in[0];
    const float* Wt     = (const float*)d_in[1];
    const int*   ntypes = (const int*)d_in[2];
    const float* pEw    = (const float*)d_in[3];
    const float* pIw    = (const float*)d_in[4];
    const float* pEvth  = (const float*)d_in[5];
    const float* pIvth  = (const float*)d_in[6];
    const int*   pnst   = (const int*)d_in[7];
    float* out = (float*)d_out;
    char* ws = (char*)d_ws;

    if (ws_size >= WS_NEEDED) {
        unsigned long long* maskbuf = (unsigned long long*)ws;
        unsigned int*       flags   = (unsigned int*)(ws + FLAG_OFF);

        lif_dfinit<<<dim3(64), dim3(256), 0, stream>>>(maskbuf, flags);

        void* args[] = { (void*)&inputs, (void*)&Wt, (void*)&ntypes,
                         (void*)&pEw, (void*)&pIw, (void*)&pEvth, (void*)&pIvth,
                         (void*)&pnst, (void*)&out, (void*)&maskbuf, (void*)&flags };
        hipLaunchCooperativeKernel((const void*)lif_persist, dim3(NWG), dim3(TPB),
                                   args, 0, stream);
    } else {
        float* scale = (float*)(ws);
        float* v     = (float*)(ws + 32768);
        float* I     = (float*)(ws + 65536);
        unsigned long long* mask0 = (unsigned long long*)(ws + 98304);
        unsigned long long* mask1 = (unsigned long long*)(ws + 99328);

        lif_init<<<dim3((N_NEUR + 255) / 256), dim3(256), 0, stream>>>(
            ntypes, pEw, pIw, scale, v, I, mask0, mask1);
        for (int t = 0; t < N_STEPS; ++t) {
            const unsigned long long* min_  = (t & 1) ? mask1 : mask0;
            unsigned long long*       mout_ = (t & 1) ? mask0 : mask1;
            lif_step<<<dim3(NWG), dim3(TPB), 0, stream>>>(
                inputs, Wt, ntypes, pEvth, pIvth, pnst,
                out, scale, v, I, min_, mout_, t);
        }
    }
}

// Round 5
// 5011.680 us; speedup vs baseline: 1.1296x; 1.1296x over previous
//
#include <hip/hip_runtime.h>

// LIF recurrent network — persistent dataflow kernel, fence-free sync.
// 128 WGs x 512 threads (8 waves), cooperative launch for co-residency only.
// Per-step mask buffers maskbuf[t][128] (u64) + flags[t][128] (u32 = t+1).
// Producer ordering: mask atomic-store RELAXED(agent) -> s_waitcnt vmcnt(0)
// (store-ack at the L3 coherence point) -> flag atomic-store RELAXED(agent).
// No release fence -> no buffer_wbl2 L2 writeback on the critical path;
// trace writes happen AFTER the flag store (nobody reads them).
// Consumer: wave w spin-polls its 16 producer flags with RELAXED atomic
// loads, decodes wave-locally (fixed order -> deterministic FP sums),
// gathers with an 8-slot predicated unroll (depth-1 L3 latency), one
// __syncthreads/step, parity-double-buffered s_red.
// Fallback to chained per-step kernels if ws_size is too small.

constexpr int N_NEUR  = 8192;
constexpr int NWORDS  = N_NEUR / 64;   // 128 mask words
constexpr int NWG     = 128;
constexpr int NW      = 8;             // waves per WG
constexpr int TPB     = NW * 64;       // 512
constexpr int QP      = NWORDS / NW;   // 16 producer words per wave
constexpr int N_STEPS = 500;

// ws layout (persistent path)
constexpr size_t MASK_BYTES = (size_t)(N_STEPS + 1) * NWORDS * 8;  // 513,024
constexpr size_t FLAG_OFF   = MASK_BYTES;
constexpr size_t FLAG_BYTES = (size_t)(N_STEPS + 1) * NWORDS * 4;  // 256,512
constexpr size_t WS_NEEDED  = FLAG_OFF + FLAG_BYTES;

// ---------------- persistent path ----------------

__global__ __launch_bounds__(256) void lif_dfinit(
    unsigned long long* __restrict__ maskbuf,
    unsigned int*       __restrict__ flags)
{
    const int i = blockIdx.x * blockDim.x + threadIdx.x;
    const int nflags = (N_STEPS + 1) * NWORDS;
    for (int k = i; k < nflags; k += gridDim.x * blockDim.x)
        flags[k] = (k < NWORDS) ? 1u : 0u;     // step-0 masks valid
    if (i < NWORDS) maskbuf[i] = 0ull;         // no spikes enter step 0
}

__global__ __launch_bounds__(TPB) void lif_persist(
    const float* __restrict__ inputs,
    const float* __restrict__ Wt,          // [N][N] row-major, row = presyn
    const int*   __restrict__ ntypes,
    const float* __restrict__ pEw,
    const float* __restrict__ pIw,
    const float* __restrict__ pEvth,
    const float* __restrict__ pIvth,
    const int*   __restrict__ pnsteps,
    float*       __restrict__ out,         // (2, n_steps, N) f32
    unsigned long long* __restrict__ maskbuf,
    unsigned int*       __restrict__ flags)
{
    const int tid  = threadIdx.x;
    const int g    = blockIdx.x;
    const int w    = tid >> 6;
    const int lane = tid & 63;
    const int c    = (g << 6) + lane;      // column owned by this lane

    __shared__ float          s_scale[N_NEUR];      // 32 KiB
    __shared__ unsigned short s_idx[NW][QP * 64];   // 16 KiB
    __shared__ float          s_sw[NW][QP * 64];    // 32 KiB
    __shared__ float          s_red[2][NW][64];     // 4 KiB

    const float Ew = *pEw, Iw = *pIw;
    for (int i = tid; i < N_NEUR; i += TPB)
        s_scale[i] = (ntypes[i] == 1) ? Ew : -Iw;

    float v_st = 0.f, I_st = 0.f, inp = 0.f, vth = 0.f;
    if (tid < 64) {
        inp = inputs[c];
        vth = (ntypes[c] == 1) ? *pEvth : *pIvth;
    }
    const int n_steps = min(*pnsteps, N_STEPS);
    const float alpha = expf(-0.1f);   // exp(-DT/TAU_M)
    const float beta  = expf(-0.2f);   // exp(-DT/TAU_I)
    __syncthreads();

    for (int t = 0; t < n_steps; ++t) {
        // ---- spin-poll this wave's 16 producer flags (RELAXED, no sleep) ----
        const unsigned tag = (unsigned)(t + 1);
        const int fbase = t * NWORDS + w * QP;
        bool done = (lane >= QP);
        for (;;) {
            if (!done)
                done = (__hip_atomic_load(&flags[fbase + lane], __ATOMIC_RELAXED,
                                          __HIP_MEMORY_SCOPE_AGENT) == tag);
            if (__all(done)) break;
        }
        unsigned long long word = 0ull;
        if (lane < QP)
            word = __hip_atomic_load(&maskbuf[fbase + lane], __ATOMIC_RELAXED,
                                     __HIP_MEMORY_SCOPE_AGENT);

        // ---- wave-local decode, fixed ascending order ----
        const int cnt = __popcll(word);
        int incl = cnt;
        #pragma unroll
        for (int d = 1; d < 64; d <<= 1) {
            const int u = __shfl_up(incl, d);
            if (lane >= d) incl += u;
        }
        const int n = __shfl(incl, QP - 1);    // wave's spike count
        int p = incl - cnt;                    // exclusive prefix
        const int base = (w * QP + lane) << 6;
        while (word) {
            const int b = __builtin_ctzll(word); word &= word - 1;
            const int j = base + b;
            s_idx[w][p] = (unsigned short)j;
            s_sw[w][p]  = s_scale[j];
            ++p;
        }
        // wave-local LDS RAW: in-order within a wave (compiler lgkmcnt)

        // ---- gather: 8-slot predicated unroll -> depth-1 L3 latency ----
        float a0 = 0.f, a1 = 0.f, a2 = 0.f, a3 = 0.f;
        float a4 = 0.f, a5 = 0.f, a6 = 0.f, a7 = 0.f;
        for (int k0 = 0; k0 < n; k0 += 8) {
            if (k0 + 0 < n) a0 = fmaf(s_sw[w][k0+0], Wt[(size_t)s_idx[w][k0+0] * N_NEUR + c], a0);
            if (k0 + 1 < n) a1 = fmaf(s_sw[w][k0+1], Wt[(size_t)s_idx[w][k0+1] * N_NEUR + c], a1);
            if (k0 + 2 < n) a2 = fmaf(s_sw[w][k0+2], Wt[(size_t)s_idx[w][k0+2] * N_NEUR + c], a2);
            if (k0 + 3 < n) a3 = fmaf(s_sw[w][k0+3], Wt[(size_t)s_idx[w][k0+3] * N_NEUR + c], a3);
            if (k0 + 4 < n) a4 = fmaf(s_sw[w][k0+4], Wt[(size_t)s_idx[w][k0+4] * N_NEUR + c], a4);
            if (k0 + 5 < n) a5 = fmaf(s_sw[w][k0+5], Wt[(size_t)s_idx[w][k0+5] * N_NEUR + c], a5);
            if (k0 + 6 < n) a6 = fmaf(s_sw[w][k0+6], Wt[(size_t)s_idx[w][k0+6] * N_NEUR + c], a6);
            if (k0 + 7 < n) a7 = fmaf(s_sw[w][k0+7], Wt[(size_t)s_idx[w][k0+7] * N_NEUR + c], a7);
        }
        s_red[t & 1][w][lane] = (((a0 + a1) + (a2 + a3)) + ((a4 + a5) + (a6 + a7)));
        __syncthreads();

        // ---- wave 0: update register state, produce t+1, then traces ----
        if (tid < 64) {
            const float rec = (((s_red[t & 1][0][lane] + s_red[t & 1][1][lane])  +
                                (s_red[t & 1][2][lane] + s_red[t & 1][3][lane])) +
                               ((s_red[t & 1][4][lane] + s_red[t & 1][5][lane])  +
                                (s_red[t & 1][6][lane] + s_red[t & 1][7][lane])));
            I_st = beta * I_st + rec;
            const float vn = alpha * v_st + (1.0f - alpha) * (I_st + inp);
            const bool  spk = (vn >= vth);
            v_st = spk ? 0.0f : vn;

            const unsigned long long m = __ballot(spk);
            if (lane == 0) {
                const int ni = (t + 1) * NWORDS + g;
                __hip_atomic_store(&maskbuf[ni], m, __ATOMIC_RELAXED,
                                   __HIP_MEMORY_SCOPE_AGENT);
                // store-ack at coherence point orders mask before flag,
                // without the release fence's buffer_wbl2.
                asm volatile("s_waitcnt vmcnt(0)" ::: "memory");
                __hip_atomic_store(&flags[ni], (unsigned)(t + 2), __ATOMIC_RELAXED,
                                   __HIP_MEMORY_SCOPE_AGENT);
            }
            // traces: consumed by nobody -> off the critical path
            out[(size_t)t * N_NEUR + c] = v_st;
            out[(size_t)n_steps * N_NEUR + (size_t)t * N_NEUR + c] = spk ? 1.0f : 0.0f;
        }
        // s_red parity + the cross-WG flag dependency chain make barrier-free
        // reuse safe: no wave can reach step t+2 before every WG's wave 0
        // has consumed its step-t s_red (its t+1 flag gates them).
    }
}

// ---------------- fallback path (round-3 chained nodes) ----------------

__global__ __launch_bounds__(256) void lif_init(
    const int* __restrict__ ntypes,
    const float* __restrict__ pEw, const float* __restrict__ pIw,
    float* __restrict__ scale, float* __restrict__ v, float* __restrict__ I,
    unsigned long long* __restrict__ mask0, unsigned long long* __restrict__ mask1)
{
    const int i = blockIdx.x * blockDim.x + threadIdx.x;
    if (i < N_NEUR) {
        scale[i] = (ntypes[i] == 1) ? *pEw : -(*pIw);
        v[i] = 0.0f; I[i] = 0.0f;
    }
    if (i < NWORDS) { mask0[i] = 0ull; mask1[i] = 0ull; }
}

__global__ __launch_bounds__(256) void lif_step(
    const float* __restrict__ inputs, const float* __restrict__ Wt,
    const int* __restrict__ ntypes,
    const float* __restrict__ pEvth, const float* __restrict__ pIvth,
    const int* __restrict__ pnsteps, float* __restrict__ out,
    const float* __restrict__ scale, float* __restrict__ v, float* __restrict__ I,
    const unsigned long long* __restrict__ mask_in,
    unsigned long long* __restrict__ mask_out, int t)
{
    const int tid = threadIdx.x, g = blockIdx.x, w = tid >> 6, lane = tid & 63;
    const int c = (g << 6) + lane;

    __shared__ float s_scale[N_NEUR];
    __shared__ unsigned short s_idx2[N_NEUR];
    __shared__ float s_red2[4][64];
    __shared__ int s_ws[2];

    unsigned long long word = 0ull;
    if (tid < NWORDS) word = mask_in[tid];

    const float4* sc4 = (const float4*)scale;
    float4* ss4 = (float4*)s_scale;
    #pragma unroll
    for (int i = 0; i < 8; ++i) ss4[tid + (i << 8)] = sc4[tid + (i << 8)];

    float v_old = 0.f, I_old = 0.f, inp = 0.f, vth = 0.f;
    if (tid < 64) {
        v_old = v[c]; I_old = I[c]; inp = inputs[c];
        vth = (ntypes[c] == 1) ? *pEvth : *pIvth;
    }
    const int n_steps = *pnsteps;

    int cnt = 0;
    if (tid < NWORDS) cnt = __popcll(word);
    int incl = cnt;
    #pragma unroll
    for (int d = 1; d < 64; d <<= 1) {
        const int u = __shfl_up(incl, d);
        if (lane >= d) incl += u;
    }
    if (w < 2 && lane == 63) s_ws[w] = incl;
    __syncthreads();

    const int n = s_ws[0] + s_ws[1];
    if (tid < NWORDS) {
        int p = ((w == 1) ? s_ws[0] : 0) + incl - cnt;
        const int base = tid << 6;
        while (word) {
            const int b = __builtin_ctzll(word); word &= word - 1;
            s_idx2[p++] = (unsigned short)(base + b);
        }
    }
    __syncthreads();

    float a0 = 0.f, a1 = 0.f, a2 = 0.f, a3 = 0.f;
    int k = w;
    for (; k + 12 < n; k += 16) {
        const int j0 = s_idx2[k], j1 = s_idx2[k + 4];
        const int j2 = s_idx2[k + 8], j3 = s_idx2[k + 12];
        a0 = fmaf(s_scale[j0], Wt[(size_t)j0 * N_NEUR + c], a0);
        a1 = fmaf(s_scale[j1], Wt[(size_t)j1 * N_NEUR + c], a1);
        a2 = fmaf(s_scale[j2], Wt[(size_t)j2 * N_NEUR + c], a2);
        a3 = fmaf(s_scale[j3], Wt[(size_t)j3 * N_NEUR + c], a3);
    }
    for (; k < n; k += 4) {
        const int j = s_idx2[k];
        a0 = fmaf(s_scale[j], Wt[(size_t)j * N_NEUR + c], a0);
    }
    s_red2[w][lane] = (a0 + a1) + (a2 + a3);
    __syncthreads();

    if (tid < 64) {
        const float rec = (s_red2[0][lane] + s_red2[1][lane]) +
                          (s_red2[2][lane] + s_red2[3][lane]);
        const float alpha = expf(-0.1f), beta = expf(-0.2f);
        const float I_new = beta * I_old + rec;
        const float vn = alpha * v_old + (1.0f - alpha) * (I_new + inp);
        const bool spk = (vn >= vth);
        const float vr = spk ? 0.0f : vn;
        if (t < n_steps) {
            out[(size_t)t * N_NEUR + c] = vr;
            out[(size_t)n_steps * N_NEUR + (size_t)t * N_NEUR + c] = spk ? 1.0f : 0.0f;
            v[c] = vr; I[c] = I_new;
            const unsigned long long m = __ballot(spk);
            if (lane == 0) mask_out[g] = m;
        }
    }
}

extern "C" void kernel_launch(void* const* d_in, const int* in_sizes, int n_in,
                              void* d_out, int out_size, void* d_ws, size_t ws_size,
                              hipStream_t stream) {
    const float* inputs = (const float*)d_in[0];
    const float* Wt     = (const float*)d_in[1];
    const int*   ntypes = (const int*)d_in[2];
    const float* pEw    = (const float*)d_in[3];
    const float* pIw    = (const float*)d_in[4];
    const float* pEvth  = (const float*)d_in[5];
    const float* pIvth  = (const float*)d_in[6];
    const int*   pnst   = (const int*)d_in[7];
    float* out = (float*)d_out;
    char* ws = (char*)d_ws;

    if (ws_size >= WS_NEEDED) {
        unsigned long long* maskbuf = (unsigned long long*)ws;
        unsigned int*       flags   = (unsigned int*)(ws + FLAG_OFF);

        lif_dfinit<<<dim3(64), dim3(256), 0, stream>>>(maskbuf, flags);

        void* args[] = { (void*)&inputs, (void*)&Wt, (void*)&ntypes,
                         (void*)&pEw, (void*)&pIw, (void*)&pEvth, (void*)&pIvth,
                         (void*)&pnst, (void*)&out, (void*)&maskbuf, (void*)&flags };
        hipLaunchCooperativeKernel((const void*)lif_persist, dim3(NWG), dim3(TPB),
                                   args, 0, stream);
    } else {
        float* scale = (float*)(ws);
        float* v     = (float*)(ws + 32768);
        float* I     = (float*)(ws + 65536);
        unsigned long long* mask0 = (unsigned long long*)(ws + 98304);
        unsigned long long* mask1 = (unsigned long long*)(ws + 99328);

        lif_init<<<dim3((N_NEUR + 255) / 256), dim3(256), 0, stream>>>(
            ntypes, pEw, pIw, scale, v, I, mask0, mask1);
        for (int t = 0; t < N_STEPS; ++t) {
            const unsigned long long* min_  = (t & 1) ? mask1 : mask0;
            unsigned long long*       mout_ = (t & 1) ? mask0 : mask1;
            lif_step<<<dim3(NWG), dim3(256), 0, stream>>>(
                inputs, Wt, ntypes, pEvth, pIvth, pnst,
                out, scale, v, I, min_, mout_, t);
        }
    }
}

// Round 6
// 4058.797 us; speedup vs baseline: 1.3948x; 1.2348x over previous
//
#include <hip/hip_runtime.h>

// LIF recurrent network as 500 chained graph nodes (one kernel per step).
// Inter-kernel dependency = the global sync (empirically cheaper than any
// intra-kernel polled-coherence scheme: R4/R5 measured ~8us one-way).
// Step kernel: 128 WGs x 512 threads (8 waves); WG g owns columns
// [g*64, g*64+64). Wave w loads+decodes its own 16 mask words (wave-local,
// fixed ascending order -> deterministic sums), gathers its sublist with 8
// predicated accumulator slots (depth-1 memory latency). Per-slot scale is
// wave-uniform -> broadcast-coalesced global load fused into the fmaf.
// One __syncthreads; wave 0 reduces, updates state, writes traces + mask.

constexpr int N_NEUR  = 8192;
constexpr int NWORDS  = N_NEUR / 64;   // 128 mask words
constexpr int NWG     = 128;
constexpr int NW      = 8;             // waves per WG
constexpr int TPB     = NW * 64;       // 512
constexpr int QP      = NWORDS / NW;   // 16 mask words per wave
constexpr int N_STEPS = 500;

__global__ __launch_bounds__(256) void lif_init(
    const int*   __restrict__ ntypes,
    const float* __restrict__ pEw,
    const float* __restrict__ pIw,
    float* __restrict__ scale,
    float* __restrict__ v,
    float* __restrict__ I,
    unsigned long long* __restrict__ mask0,
    unsigned long long* __restrict__ mask1)
{
    const int i = blockIdx.x * blockDim.x + threadIdx.x;
    if (i < N_NEUR) {
        scale[i] = (ntypes[i] == 1) ? *pEw : -(*pIw);
        v[i] = 0.0f;
        I[i] = 0.0f;
    }
    if (i < NWORDS) { mask0[i] = 0ull; mask1[i] = 0ull; }
}

__global__ __launch_bounds__(TPB) void lif_step(
    const float* __restrict__ inputs,
    const float* __restrict__ Wt,          // [N][N] row-major, row = presyn
    const int*   __restrict__ ntypes,
    const float* __restrict__ pEvth,
    const float* __restrict__ pIvth,
    const int*   __restrict__ pnsteps,
    float* __restrict__ out,               // (2, n_steps, N) f32
    const float* __restrict__ scale,       // ws: per-presyn-row scale
    float* __restrict__ v,
    float* __restrict__ I,
    const unsigned long long* __restrict__ mask_in,
    unsigned long long* __restrict__ mask_out,
    int t)
{
    const int tid  = threadIdx.x;
    const int g    = blockIdx.x;
    const int w    = tid >> 6;
    const int lane = tid & 63;
    const int c    = (g << 6) + lane;      // column owned by this lane

    __shared__ unsigned short s_idx[NW][QP * 64];   // 16 KiB
    __shared__ float          s_red[NW][64];        //  2 KiB

    // ---- critical-path load first: this wave's 16 mask words ----
    unsigned long long word = 0ull;
    if (lane < QP) word = mask_in[w * QP + lane];

    // ---- independent state loads (wave 0), overlapped with mask latency ----
    float v_old = 0.f, I_old = 0.f, inp = 0.f, vth = 0.f;
    if (tid < 64) {
        v_old = v[c];
        I_old = I[c];
        inp   = inputs[c];
        vth   = (ntypes[c] == 1) ? *pEvth : *pIvth;
    }
    const int n_steps = *pnsteps;          // consumed only at the write phase

    // ---- wave-local decode, fixed ascending order ----
    const int cnt = __popcll(word);
    int incl = cnt;
    #pragma unroll
    for (int d = 1; d < 64; d <<= 1) {
        const int u = __shfl_up(incl, d);
        if (lane >= d) incl += u;
    }
    const int n = __shfl(incl, QP - 1);    // this wave's spike count
    int p = incl - cnt;                    // exclusive prefix
    const int base = (w * QP + lane) << 6;
    while (word) {
        const int b = __builtin_ctzll(word); word &= word - 1;
        s_idx[w][p++] = (unsigned short)(base + b);
    }
    // wave-local LDS RAW: in-order within a wave (compiler lgkmcnt)

    // ---- gather: 8 predicated slots -> depth-1 latency; scale load is
    //      wave-uniform (broadcast-coalesced), fused into the fmaf ----
    float a0 = 0.f, a1 = 0.f, a2 = 0.f, a3 = 0.f;
    float a4 = 0.f, a5 = 0.f, a6 = 0.f, a7 = 0.f;
    for (int k0 = 0; k0 < n; k0 += 8) {
        if (k0 + 0 < n) { const int j = s_idx[w][k0+0]; a0 = fmaf(scale[j], Wt[(size_t)j * N_NEUR + c], a0); }
        if (k0 + 1 < n) { const int j = s_idx[w][k0+1]; a1 = fmaf(scale[j], Wt[(size_t)j * N_NEUR + c], a1); }
        if (k0 + 2 < n) { const int j = s_idx[w][k0+2]; a2 = fmaf(scale[j], Wt[(size_t)j * N_NEUR + c], a2); }
        if (k0 + 3 < n) { const int j = s_idx[w][k0+3]; a3 = fmaf(scale[j], Wt[(size_t)j * N_NEUR + c], a3); }
        if (k0 + 4 < n) { const int j = s_idx[w][k0+4]; a4 = fmaf(scale[j], Wt[(size_t)j * N_NEUR + c], a4); }
        if (k0 + 5 < n) { const int j = s_idx[w][k0+5]; a5 = fmaf(scale[j], Wt[(size_t)j * N_NEUR + c], a5); }
        if (k0 + 6 < n) { const int j = s_idx[w][k0+6]; a6 = fmaf(scale[j], Wt[(size_t)j * N_NEUR + c], a6); }
        if (k0 + 7 < n) { const int j = s_idx[w][k0+7]; a7 = fmaf(scale[j], Wt[(size_t)j * N_NEUR + c], a7); }
    }
    s_red[w][lane] = (((a0 + a1) + (a2 + a3)) + ((a4 + a5) + (a6 + a7)));
    __syncthreads();

    // ---- wave 0: reduce, update state, traces, next mask ----
    if (tid < 64) {
        const float rec = (((s_red[0][lane] + s_red[1][lane])  +
                            (s_red[2][lane] + s_red[3][lane])) +
                           ((s_red[4][lane] + s_red[5][lane])  +
                            (s_red[6][lane] + s_red[7][lane])));

        const float alpha = expf(-0.1f);   // exp(-DT/TAU_M)
        const float beta  = expf(-0.2f);   // exp(-DT/TAU_I)

        const float I_new = beta * I_old + rec;
        const float vn    = alpha * v_old + (1.0f - alpha) * (I_new + inp);
        const bool  spk   = (vn >= vth);
        const float vr    = spk ? 0.0f : vn;

        if (t < n_steps) {
            const unsigned long long m = __ballot(spk);
            if (lane == 0) mask_out[g] = m;
            out[(size_t)t * N_NEUR + c] = vr;
            out[(size_t)n_steps * N_NEUR + (size_t)t * N_NEUR + c] = spk ? 1.0f : 0.0f;
            v[c] = vr;
            I[c] = I_new;
        }
    }
}

extern "C" void kernel_launch(void* const* d_in, const int* in_sizes, int n_in,
                              void* d_out, int out_size, void* d_ws, size_t ws_size,
                              hipStream_t stream) {
    const float* inputs = (const float*)d_in[0];
    const float* Wt     = (const float*)d_in[1];
    const int*   ntypes = (const int*)d_in[2];
    const float* pEw    = (const float*)d_in[3];
    const float* pIw    = (const float*)d_in[4];
    const float* pEvth  = (const float*)d_in[5];
    const float* pIvth  = (const float*)d_in[6];
    const int*   pnst   = (const int*)d_in[7];
    float* out = (float*)d_out;

    char* ws = (char*)d_ws;
    float*              scale = (float*)(ws);                       // 32 KiB
    float*              v     = (float*)(ws + 32768);               // 32 KiB
    float*              I     = (float*)(ws + 65536);               // 32 KiB
    unsigned long long* mask0 = (unsigned long long*)(ws + 98304);  // 1 KiB
    unsigned long long* mask1 = (unsigned long long*)(ws + 99328);  // 1 KiB

    lif_init<<<dim3((N_NEUR + 255) / 256), dim3(256), 0, stream>>>(
        ntypes, pEw, pIw, scale, v, I, mask0, mask1);

    for (int t = 0; t < N_STEPS; ++t) {
        const unsigned long long* min_  = (t & 1) ? mask1 : mask0;
        unsigned long long*       mout_ = (t & 1) ? mask0 : mask1;
        lif_step<<<dim3(NWG), dim3(TPB), 0, stream>>>(
            inputs, Wt, ntypes, pEvth, pIvth, pnst,
            out, scale, v, I, min_, mout_, t);
    }
}

// Round 7
// 2482.607 us; speedup vs baseline: 2.2804x; 1.6349x over previous
//
#include <hip/hip_runtime.h>

// LIF recurrent network as 500 chained graph nodes (one kernel per step).
// Inter-kernel dependency = the global sync (cheapest measured: R4/R5
// intra-kernel polled coherence cost ~8us one-way vs ~4us node gap).
// Step kernel: 128 WGs x 256 threads (4 waves); WG g owns columns
// [g*64, g*64+64). Wave w loads+decodes its own 32 mask words into a
// private list (fixed ascending order -> deterministic sums), pads the
// list to a multiple of 8 with zero-scale entries, then gathers with 8
// UNCONDITIONAL slots (branch-free -> all 8 rows in flight; R6's
// predicated version serialized into 8 latency rounds and regressed).
// Zero barriers before the gather; one __syncthreads before the reduce.

constexpr int N_NEUR  = 8192;
constexpr int NWORDS  = N_NEUR / 64;   // 128 mask words
constexpr int NWG     = 128;
constexpr int NW      = 4;             // waves per WG
constexpr int TPB     = NW * 64;       // 256
constexpr int QP      = NWORDS / NW;   // 32 mask words per wave
constexpr int WCAP    = QP * 64 + 8;   // per-wave list capacity (+pad margin)
constexpr int N_STEPS = 500;

__global__ __launch_bounds__(256) void lif_init(
    const int*   __restrict__ ntypes,
    const float* __restrict__ pEw,
    const float* __restrict__ pIw,
    float* __restrict__ scale,
    float* __restrict__ v,
    float* __restrict__ I,
    unsigned long long* __restrict__ mask0,
    unsigned long long* __restrict__ mask1)
{
    const int i = blockIdx.x * blockDim.x + threadIdx.x;
    if (i < N_NEUR) {
        scale[i] = (ntypes[i] == 1) ? *pEw : -(*pIw);
        v[i] = 0.0f;
        I[i] = 0.0f;
    }
    if (i < NWORDS) { mask0[i] = 0ull; mask1[i] = 0ull; }
}

__global__ __launch_bounds__(TPB) void lif_step(
    const float* __restrict__ inputs,
    const float* __restrict__ Wt,          // [N][N] row-major, row = presyn
    const int*   __restrict__ ntypes,
    const float* __restrict__ pEvth,
    const float* __restrict__ pIvth,
    const int*   __restrict__ pnsteps,
    float* __restrict__ out,               // (2, n_steps, N) f32
    const float* __restrict__ scale,       // ws: per-presyn-row scale
    float* __restrict__ v,
    float* __restrict__ I,
    const unsigned long long* __restrict__ mask_in,
    unsigned long long* __restrict__ mask_out,
    int t)
{
    const int tid  = threadIdx.x;
    const int g    = blockIdx.x;
    const int w    = tid >> 6;
    const int lane = tid & 63;
    const int c    = (g << 6) + lane;      // column owned by this lane

    __shared__ float          s_scale[N_NEUR];   // 32 KiB
    __shared__ unsigned short s_idx[NW][WCAP];   // ~16 KiB
    __shared__ float          s_sw[NW][WCAP];    // ~32 KiB
    __shared__ float          s_red[NW][64];     //  1 KiB

    // ---- critical-path load first: this wave's 32 mask words ----
    unsigned long long word = 0ull;
    if (lane < QP) word = mask_in[w * QP + lane];

    // ---- wave-aligned scale staging: wave w stages its own 2048 floats ----
    // (decode below reads only this wave's slice -> no barrier needed;
    //  global->ds_write->ds_read ordering is in-order within a wave.)
    {
        const float4* sc4 = (const float4*)scale;
        float4*       ss4 = (float4*)s_scale;
        #pragma unroll
        for (int i = 0; i < 8; ++i)
            ss4[(w << 9) + (i << 6) + lane] = sc4[(w << 9) + (i << 6) + lane];
    }

    // ---- independent state loads (wave 0), overlapped with mask latency ----
    float v_old = 0.f, I_old = 0.f, inp = 0.f, vth = 0.f;
    if (tid < 64) {
        v_old = v[c];
        I_old = I[c];
        inp   = inputs[c];
        vth   = (ntypes[c] == 1) ? *pEvth : *pIvth;
    }
    const int n_steps = *pnsteps;          // consumed only at the write phase

    // ---- wave-local decode, fixed ascending order ----
    const int cnt = __popcll(word);
    int incl = cnt;
    #pragma unroll
    for (int d = 1; d < 64; d <<= 1) {
        const int u = __shfl_up(incl, d);
        if (lane >= d) incl += u;
    }
    const int n = __shfl(incl, QP - 1);    // this wave's spike count
    int p = incl - cnt;                    // exclusive prefix
    const int base = (w * QP + lane) << 6;
    while (word) {
        const int b = __builtin_ctzll(word); word &= word - 1;
        const int j = base + b;
        s_idx[w][p] = (unsigned short)j;
        s_sw[w][p]  = s_scale[j];          // wave-own slice, in-order
        ++p;
    }

    // ---- pad to a multiple of 8 with zero-scale entries (fmaf no-op) ----
    const int npad = (n + 7) & ~7;
    if (lane < npad - n) {
        s_idx[w][n + lane] = 0;
        s_sw[w][n + lane]  = 0.0f;
    }

    // ---- gather: 8 unconditional slots, all rows in flight ----
    float a0 = 0.f, a1 = 0.f, a2 = 0.f, a3 = 0.f;
    float a4 = 0.f, a5 = 0.f, a6 = 0.f, a7 = 0.f;
    for (int k0 = 0; k0 < npad; k0 += 8) {
        const int j0 = s_idx[w][k0+0], j1 = s_idx[w][k0+1];
        const int j2 = s_idx[w][k0+2], j3 = s_idx[w][k0+3];
        const int j4 = s_idx[w][k0+4], j5 = s_idx[w][k0+5];
        const int j6 = s_idx[w][k0+6], j7 = s_idx[w][k0+7];
        const float w0s = s_sw[w][k0+0], w1s = s_sw[w][k0+1];
        const float w2s = s_sw[w][k0+2], w3s = s_sw[w][k0+3];
        const float w4s = s_sw[w][k0+4], w5s = s_sw[w][k0+5];
        const float w6s = s_sw[w][k0+6], w7s = s_sw[w][k0+7];
        a0 = fmaf(w0s, Wt[(size_t)j0 * N_NEUR + c], a0);
        a1 = fmaf(w1s, Wt[(size_t)j1 * N_NEUR + c], a1);
        a2 = fmaf(w2s, Wt[(size_t)j2 * N_NEUR + c], a2);
        a3 = fmaf(w3s, Wt[(size_t)j3 * N_NEUR + c], a3);
        a4 = fmaf(w4s, Wt[(size_t)j4 * N_NEUR + c], a4);
        a5 = fmaf(w5s, Wt[(size_t)j5 * N_NEUR + c], a5);
        a6 = fmaf(w6s, Wt[(size_t)j6 * N_NEUR + c], a6);
        a7 = fmaf(w7s, Wt[(size_t)j7 * N_NEUR + c], a7);
    }
    s_red[w][lane] = (((a0 + a1) + (a2 + a3)) + ((a4 + a5) + (a6 + a7)));
    __syncthreads();

    // ---- wave 0: reduce, update state, traces, next mask ----
    if (tid < 64) {
        const float rec = (s_red[0][lane] + s_red[1][lane]) +
                          (s_red[2][lane] + s_red[3][lane]);

        const float alpha = expf(-0.1f);   // exp(-DT/TAU_M)
        const float beta  = expf(-0.2f);   // exp(-DT/TAU_I)

        const float I_new = beta * I_old + rec;
        const float vn    = alpha * v_old + (1.0f - alpha) * (I_new + inp);
        const bool  spk   = (vn >= vth);
        const float vr    = spk ? 0.0f : vn;

        if (t < n_steps) {
            const unsigned long long m = __ballot(spk);
            if (lane == 0) mask_out[g] = m;
            out[(size_t)t * N_NEUR + c] = vr;
            out[(size_t)n_steps * N_NEUR + (size_t)t * N_NEUR + c] = spk ? 1.0f : 0.0f;
            v[c] = vr;
            I[c] = I_new;
        }
    }
}

extern "C" void kernel_launch(void* const* d_in, const int* in_sizes, int n_in,
                              void* d_out, int out_size, void* d_ws, size_t ws_size,
                              hipStream_t stream) {
    const float* inputs = (const float*)d_in[0];
    const float* Wt     = (const float*)d_in[1];
    const int*   ntypes = (const int*)d_in[2];
    const float* pEw    = (const float*)d_in[3];
    const float* pIw    = (const float*)d_in[4];
    const float* pEvth  = (const float*)d_in[5];
    const float* pIvth  = (const float*)d_in[6];
    const int*   pnst   = (const int*)d_in[7];
    float* out = (float*)d_out;

    char* ws = (char*)d_ws;
    float*              scale = (float*)(ws);                       // 32 KiB
    float*              v     = (float*)(ws + 32768);               // 32 KiB
    float*              I     = (float*)(ws + 65536);               // 32 KiB
    unsigned long long* mask0 = (unsigned long long*)(ws + 98304);  // 1 KiB
    unsigned long long* mask1 = (unsigned long long*)(ws + 99328);  // 1 KiB

    lif_init<<<dim3((N_NEUR + 255) / 256), dim3(256), 0, stream>>>(
        ntypes, pEw, pIw, scale, v, I, mask0, mask1);

    for (int t = 0; t < N_STEPS; ++t) {
        const unsigned long long* min_  = (t & 1) ? mask1 : mask0;
        unsigned long long*       mout_ = (t & 1) ? mask0 : mask1;
        lif_step<<<dim3(NWG), dim3(TPB), 0, stream>>>(
            inputs, Wt, ntypes, pEvth, pIvth, pnst,
            out, scale, v, I, min_, mout_, t);
    }
}

// Round 8
// 2304.424 us; speedup vs baseline: 2.4567x; 1.0773x over previous
//
#include <hip/hip_runtime.h>

// LIF recurrent network as 500 chained graph nodes (one kernel per step).
// Inter-kernel dependency = the global sync (cheapest measured: node gap
// ~3us vs ~8us one-way intra-kernel polled coherence, R4/R5).
// Step kernel: 128 WGs x 256 threads (4 waves); WG g owns columns
// [g*64, g*64+64). Wave w decodes its own 32 mask words into a private
// list (fixed ascending order -> deterministic sums), pads to a multiple
// of 16, gathers with 16 UNCONDITIONAL slots (one L3 latency round at
// typical ~10 spikes/wave). Per-slot scale is a wave-uniform global load
// issued concurrently with the row load; pad slots are zeroed by a
// post-load cndmask (loads never predicated -- R6's lesson). Per-neuron
// state packed as float4 {v, I, inp, vth} -> one 16B load, one 8B store.
// Zero barriers before the gather; one __syncthreads before the reduce.

constexpr int N_NEUR  = 8192;
constexpr int NWORDS  = N_NEUR / 64;   // 128 mask words
constexpr int NWG     = 128;
constexpr int NW      = 4;             // waves per WG
constexpr int TPB     = NW * 64;       // 256
constexpr int QP      = NWORDS / NW;   // 32 mask words per wave
constexpr int WCAP    = QP * 64 + 16;  // per-wave list capacity (+pad margin)
constexpr int N_STEPS = 500;

__global__ __launch_bounds__(256) void lif_init(
    const float* __restrict__ inputs,
    const int*   __restrict__ ntypes,
    const float* __restrict__ pEw,
    const float* __restrict__ pIw,
    const float* __restrict__ pEvth,
    const float* __restrict__ pIvth,
    float*  __restrict__ scale,
    float4* __restrict__ state,            // {v, I, inp, vth}
    unsigned long long* __restrict__ mask0,
    unsigned long long* __restrict__ mask1)
{
    const int i = blockIdx.x * blockDim.x + threadIdx.x;
    if (i < N_NEUR) {
        const bool exc = (ntypes[i] == 1);
        scale[i] = exc ? *pEw : -(*pIw);
        state[i] = make_float4(0.0f, 0.0f, inputs[i], exc ? *pEvth : *pIvth);
    }
    if (i < NWORDS) { mask0[i] = 0ull; mask1[i] = 0ull; }
}

__global__ __launch_bounds__(TPB) void lif_step(
    const float* __restrict__ Wt,          // [N][N] row-major, row = presyn
    const int*   __restrict__ pnsteps,
    float* __restrict__ out,               // (2, n_steps, N) f32
    const float* __restrict__ scale,       // ws: per-presyn-row scale
    float4* __restrict__ state,            // ws: {v, I, inp, vth}
    const unsigned long long* __restrict__ mask_in,
    unsigned long long* __restrict__ mask_out,
    int t)
{
    const int tid  = threadIdx.x;
    const int g    = blockIdx.x;
    const int w    = tid >> 6;
    const int lane = tid & 63;
    const int c    = (g << 6) + lane;      // column owned by this lane

    __shared__ unsigned short s_idx[NW][WCAP];   // ~16.5 KiB
    __shared__ float          s_red[NW][64];     //  1 KiB

    // ---- critical-path load first: this wave's 32 mask words ----
    unsigned long long word = 0ull;
    if (lane < QP) word = mask_in[w * QP + lane];

    // ---- independent state load (wave 0): one float4 per neuron ----
    float4 st = make_float4(0.f, 0.f, 0.f, 0.f);
    if (tid < 64) st = state[c];
    const int n_steps = *pnsteps;          // consumed only at the write phase

    // ---- wave-local decode, fixed ascending order (s_idx only) ----
    const int cnt = __popcll(word);
    int incl = cnt;
    #pragma unroll
    for (int d = 1; d < 64; d <<= 1) {
        const int u = __shfl_up(incl, d);
        if (lane >= d) incl += u;
    }
    const int n = __shfl(incl, QP - 1);    // this wave's spike count
    int p = incl - cnt;                    // exclusive prefix
    const int base = (w * QP + lane) << 6;
    while (word) {
        const int b = __builtin_ctzll(word); word &= word - 1;
        s_idx[w][p++] = (unsigned short)(base + b);
    }
    // pad to a multiple of 16 (gather reads these; scale is zeroed by select)
    const int npad = (n + 15) & ~15;
    if (lane < npad - n) s_idx[w][n + lane] = 0;

    // ---- gather: 16 unconditional slots -> one latency round typical.
    //      scale[j] is wave-uniform (broadcast) and concurrent with the
    //      row load; pad slots zeroed AFTER the load via select. ----
    float a0 = 0.f, a1 = 0.f, a2 = 0.f, a3 = 0.f;
    float a4 = 0.f, a5 = 0.f, a6 = 0.f, a7 = 0.f;
    float a8 = 0.f, a9 = 0.f, aA = 0.f, aB = 0.f;
    float aC = 0.f, aD = 0.f, aE = 0.f, aF = 0.f;
    for (int k0 = 0; k0 < npad; k0 += 16) {
        #define SLOT(i, acc)                                                  \
        {                                                                     \
            const int   j = s_idx[w][k0 + (i)];                               \
            float       s = scale[j];                                         \
            const float r = Wt[(size_t)j * N_NEUR + c];                       \
            s = (k0 + (i) < n) ? s : 0.0f;                                    \
            acc = fmaf(s, r, acc);                                            \
        }
        SLOT(0, a0)  SLOT(1, a1)  SLOT(2, a2)  SLOT(3, a3)
        SLOT(4, a4)  SLOT(5, a5)  SLOT(6, a6)  SLOT(7, a7)
        SLOT(8, a8)  SLOT(9, a9)  SLOT(10, aA) SLOT(11, aB)
        SLOT(12, aC) SLOT(13, aD) SLOT(14, aE) SLOT(15, aF)
        #undef SLOT
    }
    s_red[w][lane] = ((((a0 + a1) + (a2 + a3)) + ((a4 + a5) + (a6 + a7))) +
                      (((a8 + a9) + (aA + aB)) + ((aC + aD) + (aE + aF))));
    __syncthreads();

    // ---- wave 0: reduce, update state, next mask, traces ----
    if (tid < 64) {
        const float rec = (s_red[0][lane] + s_red[1][lane]) +
                          (s_red[2][lane] + s_red[3][lane]);

        const float alpha = expf(-0.1f);   // exp(-DT/TAU_M)
        const float beta  = expf(-0.2f);   // exp(-DT/TAU_I)

        const float I_new = beta * st.y + rec;
        const float vn    = alpha * st.x + (1.0f - alpha) * (I_new + st.z);
        const bool  spk   = (vn >= st.w);
        const float vr    = spk ? 0.0f : vn;

        if (t < n_steps) {
            const unsigned long long m = __ballot(spk);
            if (lane == 0) mask_out[g] = m;
            *(float2*)&state[c] = make_float2(vr, I_new);   // v, I only
            out[(size_t)t * N_NEUR + c] = vr;
            out[(size_t)n_steps * N_NEUR + (size_t)t * N_NEUR + c] = spk ? 1.0f : 0.0f;
        }
    }
}

extern "C" void kernel_launch(void* const* d_in, const int* in_sizes, int n_in,
                              void* d_out, int out_size, void* d_ws, size_t ws_size,
                              hipStream_t stream) {
    const float* inputs = (const float*)d_in[0];
    const float* Wt     = (const float*)d_in[1];
    const int*   ntypes = (const int*)d_in[2];
    const float* pEw    = (const float*)d_in[3];
    const float* pIw    = (const float*)d_in[4];
    const float* pEvth  = (const float*)d_in[5];
    const float* pIvth  = (const float*)d_in[6];
    const int*   pnst   = (const int*)d_in[7];
    float* out = (float*)d_out;

    char* ws = (char*)d_ws;
    float*              scale = (float*)(ws);                        // 32 KiB
    float4*             state = (float4*)(ws + 32768);               // 128 KiB
    unsigned long long* mask0 = (unsigned long long*)(ws + 163840);  // 1 KiB
    unsigned long long* mask1 = (unsigned long long*)(ws + 164864);  // 1 KiB

    lif_init<<<dim3((N_NEUR + 255) / 256), dim3(256), 0, stream>>>(
        inputs, ntypes, pEw, pIw, pEvth, pIvth, scale, state, mask0, mask1);

    for (int t = 0; t < N_STEPS; ++t) {
        const unsigned long long* min_  = (t & 1) ? mask1 : mask0;
        unsigned long long*       mout_ = (t & 1) ? mask0 : mask1;
        lif_step<<<dim3(NWG), dim3(TPB), 0, stream>>>(
            Wt, pnst, out, scale, state, min_, mout_, t);
    }
}